// Round 3
// baseline (180.456 us; speedup 1.0000x reference)
//
#include <hip/hip_runtime.h>
#include <stdint.h>

// Moment features: all monomials of degree <= 4 over 16 latent dims.
// Output [8192, 4845] fp32 (~158.8 MB) -> pure HBM-write-bound.
//
// Decomposition: every channel of order k is prefix_feat(order k-1) * x[j],
// and the reference enumeration makes these runs (prefix-major, j minor).
// The order<=3 features (969 of them) are exactly output channels 0..968, so
// one constexpr (A,B)-pair table drives both the LDS compute phases and the
// store phase. Store phase: lanes read near-consecutive prefix slots
// (broadcast/consecutive words) + x slots from a 16-word window -> LDS
// conflict-free; stores are coalesced nontemporal dwordx4.

#define D      16
#define NC     4845           // 1 + 16 + 136 + 816 + 3876 = C(20,4)
#define NPAD   4864           // 19*256 chunks (padded)
#define POSPB  4              // rows per block; 4*4845 dwords = 4845 float4s
#define STRIDE 969            // LDS slots/pos: 1.0, x[16], o2[136], o3[816]

typedef float    f4_t __attribute__((ext_vector_type(4)));
typedef uint32_t u4_t __attribute__((ext_vector_type(4)));

struct Tables {
    uint32_t chunk[NPAD * 4]; // per flat dword of a 4-row group:
                              // (p*STRIDE+A) | ((p*STRIDE+B) << 16); pad = 0
};

static constexpr Tables build_tables() {
    Tables t{};
    // ---- per-channel (A = prefix slot, B = x slot), reference order ----
    unsigned short A[NC] = {}, B[NC] = {};
    int pos = 0;
    A[pos] = 0; B[pos] = 0; ++pos;                        // ones: 1*1
    for (int i = 0; i < D; ++i) { A[pos] = 0; B[pos] = (unsigned short)(1 + i); ++pos; }
    long c[D] = {};
    for (int i = 0; i < D; ++i) c[i] = 1;
    int baseprev = 1;                       // slot base of previous-order feats
    const int basecur[3] = {17, 153, 969};
    for (int it = 0; it < 3; ++it) {
        long S[D] = {};
        long acc = 0;
        for (int i = D - 1; i >= 0; --i) { acc += c[i]; S[i] = acc; }
        const long n = S[0];
        long off[D] = {};
        for (int i = 0; i < D; ++i) off[i] = n - S[i];
        for (long k = 0; k < n; ++k)                      // np.nonzero row-major
            for (int j = 0; j < D; ++j)
                if (k >= off[j]) {
                    A[pos] = (unsigned short)(baseprev + (int)k);
                    B[pos] = (unsigned short)(1 + j);
                    ++pos;
                }
        baseprev = basecur[it];
        for (int i = 0; i < D; ++i) c[i] = S[i];
    }
    // ---- expand flat dword table for a 4-row group, baking p*STRIDE ----
    for (int f = 0; f < NPAD * 4; ++f) {
        const int p = f / NC;
        const int ch = f - p * NC;
        if (p < POSPB)
            t.chunk[f] = (uint32_t)(p * STRIDE + A[ch])
                       | ((uint32_t)(p * STRIDE + B[ch]) << 16);
        else
            t.chunk[f] = 0;   // padding: reads lds[0]*lds[0], store guarded off
    }
    return t;
}

__device__ const Tables d_tables = build_tables();

__global__ __launch_bounds__(256) void moment_kernel(const float* __restrict__ in,
                                                     float* __restrict__ out) {
    __shared__ float lds[POSPB * STRIDE];   // 15504 B -> 8 blocks/CU
    const int tid = threadIdx.x;
    const int blk = blockIdx.x;
    const uint32_t* __restrict__ dtab = d_tables.chunk;

    // stage x: 4 rows * 16 floats, coalesced; plus 1.0 identity slot per row
    if (tid < 64) {
        const float v = in[(size_t)blk * (POSPB * D) + tid];
        lds[(tid >> 4) * STRIDE + 1 + (tid & 15)] = v;
    } else if (tid < 68) {
        lds[(tid - 64) * STRIDE] = 1.0f;
    }
    __syncthreads();

    // order-2 feats: 136 x 4 pos (same association as reference: x[k]*x[j])
    for (int i = tid; i < 136 * POSPB; i += 256) {
        const int ch = 17 + (i >> 2);
        const int po = (i & 3) * STRIDE;
        const uint32_t e = dtab[ch];                 // p=0 entry == raw (A,B)
        lds[po + ch] = lds[po + (e & 0xFFFFu)] * lds[po + (e >> 16)];
    }
    __syncthreads();

    // order-3 feats: 816 x 4 pos (prev * x, exact reference association)
    for (int i = tid; i < 816 * POSPB; i += 256) {
        const int ch = 153 + (i >> 2);
        const int po = (i & 3) * STRIDE;
        const uint32_t e = dtab[ch];
        lds[po + ch] = lds[po + (e & 0xFFFFu)] * lds[po + (e >> 16)];
    }
    __syncthreads();

    // store phase: 4845 float4 chunks per block, nontemporal dwordx4
    f4_t* __restrict__ ochunk = (f4_t*)(out + (size_t)blk * (NC * POSPB));
    const u4_t* __restrict__ tab4 = (const u4_t*)dtab;
    #pragma unroll 4
    for (int it2 = 0; it2 < 19; ++it2) {
        const int q = tid + it2 * 256;
        const u4_t e = tab4[q];                      // table padded to NPAD
        f4_t v;
        v.x = lds[e.x & 0xFFFFu] * lds[e.x >> 16];
        v.y = lds[e.y & 0xFFFFu] * lds[e.y >> 16];
        v.z = lds[e.z & 0xFFFFu] * lds[e.z >> 16];
        v.w = lds[e.w & 0xFFFFu] * lds[e.w >> 16];
        if (q < NC) __builtin_nontemporal_store(v, &ochunk[q]);
    }
}

extern "C" void kernel_launch(void* const* d_in, const int* in_sizes, int n_in,
                              void* d_out, int out_size, void* d_ws, size_t ws_size,
                              hipStream_t stream) {
    const float* in = (const float*)d_in[0];
    float* out = (float*)d_out;
    const int npos = in_sizes[0] / D;        // 8192
    const int nblk = npos / POSPB;           // 2048
    moment_kernel<<<nblk, 256, 0, stream>>>(in, out);
}

// Round 4
// 171.130 us; speedup vs baseline: 1.0545x; 1.0545x over previous
//
#include <hip/hip_runtime.h>
#include <stdint.h>

// Moment features: all monomials of degree <= 4 over 16 latent dims.
// Output [8192, 4845] fp32 (~158.8 MB) -> pure HBM-write-bound.
//
// Every channel of order k is prefix_feat(order k-1) * x[j]; the reference
// enumeration makes these prefix-major runs. The order<=3 features (969) are
// exactly output channels 0..968, so one constexpr (A,B) table drives both
// the LDS compute phases and the store phase. Store-phase LDS reads are
// near-consecutive/broadcast -> conflict-free. Stores: plain (L2 write-
// combined) coalesced dwordx4 — nontemporal was a measured -25% regression.
// Depth-1 table prefetch + unroll 2 pipelines the load->LDS->mul->store chain.

#define D      16
#define NC     4845           // 1 + 16 + 136 + 816 + 3876 = C(20,4)
#define NPAD   4864           // 19*256 chunks
#define NTAB   (NPAD + 256)   // +256 chunk pad so depth-1 prefetch is unguarded
#define POSPB  4              // rows per block; 4*4845 dwords = 4845 float4s
#define STRIDE 969            // LDS slots/pos: 1.0, x[16], o2[136], o3[816]

typedef float    f4_t __attribute__((ext_vector_type(4)));
typedef uint32_t u4_t __attribute__((ext_vector_type(4)));

struct alignas(16) Tables {
    uint32_t chunk[NTAB * 4]; // per flat dword of a 4-row group:
                              // (p*STRIDE+A) | ((p*STRIDE+B) << 16); pad = 0
};

static constexpr Tables build_tables() {
    Tables t{};
    // ---- per-channel (A = prefix slot, B = x slot), reference order ----
    unsigned short A[NC] = {}, B[NC] = {};
    int pos = 0;
    A[pos] = 0; B[pos] = 0; ++pos;                        // ones: 1*1
    for (int i = 0; i < D; ++i) { A[pos] = 0; B[pos] = (unsigned short)(1 + i); ++pos; }
    long c[D] = {};
    for (int i = 0; i < D; ++i) c[i] = 1;
    int baseprev = 1;                       // slot base of previous-order feats
    const int basecur[3] = {17, 153, 969};
    for (int it = 0; it < 3; ++it) {
        long S[D] = {};
        long acc = 0;
        for (int i = D - 1; i >= 0; --i) { acc += c[i]; S[i] = acc; }
        const long n = S[0];
        long off[D] = {};
        for (int i = 0; i < D; ++i) off[i] = n - S[i];
        for (long k = 0; k < n; ++k)                      // np.nonzero row-major
            for (int j = 0; j < D; ++j)
                if (k >= off[j]) {
                    A[pos] = (unsigned short)(baseprev + (int)k);
                    B[pos] = (unsigned short)(1 + j);
                    ++pos;
                }
        baseprev = basecur[it];
        for (int i = 0; i < D; ++i) c[i] = S[i];
    }
    // ---- expand flat dword table for a 4-row group, baking p*STRIDE ----
    for (int f = 0; f < NTAB * 4; ++f) {
        const int p = f / NC;
        const int ch = f - p * NC;
        if (p < POSPB)
            t.chunk[f] = (uint32_t)(p * STRIDE + A[ch])
                       | ((uint32_t)(p * STRIDE + B[ch]) << 16);
        else
            t.chunk[f] = 0;   // padding: reads lds[0]*lds[0], store guarded off
    }
    return t;
}

__device__ const Tables d_tables = build_tables();

__global__ __launch_bounds__(256, 8) void moment_kernel(const float* __restrict__ in,
                                                        float* __restrict__ out) {
    __shared__ float lds[POSPB * STRIDE];   // 15504 B -> 8 blocks/CU, 32 waves
    const int tid = threadIdx.x;
    const int blk = blockIdx.x;
    const uint32_t* __restrict__ dtab = d_tables.chunk;

    // stage x: 4 rows * 16 floats, coalesced; plus 1.0 identity slot per row
    if (tid < 64) {
        const float v = in[(size_t)blk * (POSPB * D) + tid];
        lds[(tid >> 4) * STRIDE + 1 + (tid & 15)] = v;
    } else if (tid < 68) {
        lds[(tid - 64) * STRIDE] = 1.0f;
    }
    __syncthreads();

    // order-2 feats: 136 x 4 pos (x[k]*x[j], exact reference association)
    for (int i = tid; i < 136 * POSPB; i += 256) {
        const int ch = 17 + (i >> 2);
        const int po = (i & 3) * STRIDE;
        const uint32_t e = dtab[ch];                 // p=0 entry == raw (A,B)
        lds[po + ch] = lds[po + (e & 0xFFFFu)] * lds[po + (e >> 16)];
    }
    __syncthreads();

    // order-3 feats: 816 x 4 pos (prev * x, exact reference association)
    for (int i = tid; i < 816 * POSPB; i += 256) {
        const int ch = 153 + (i >> 2);
        const int po = (i & 3) * STRIDE;
        const uint32_t e = dtab[ch];
        lds[po + ch] = lds[po + (e & 0xFFFFu)] * lds[po + (e >> 16)];
    }
    __syncthreads();

    // store phase: 4845 float4 chunks per block, plain coalesced dwordx4,
    // depth-1 table prefetch to hide the table->LDS->mul->store chain
    f4_t* __restrict__ ochunk = (f4_t*)(out + (size_t)blk * (NC * POSPB));
    const u4_t* __restrict__ tab4 = (const u4_t*)dtab;
    u4_t e = tab4[tid];
    #pragma unroll 2
    for (int it2 = 0; it2 < 19; ++it2) {
        const int q = tid + it2 * 256;
        const u4_t en = tab4[q + 256];               // always in-bounds (pad)
        f4_t v;
        v.x = lds[e.x & 0xFFFFu] * lds[e.x >> 16];
        v.y = lds[e.y & 0xFFFFu] * lds[e.y >> 16];
        v.z = lds[e.z & 0xFFFFu] * lds[e.z >> 16];
        v.w = lds[e.w & 0xFFFFu] * lds[e.w >> 16];
        if (q < NC) ochunk[q] = v;
        e = en;
    }
}

extern "C" void kernel_launch(void* const* d_in, const int* in_sizes, int n_in,
                              void* d_out, int out_size, void* d_ws, size_t ws_size,
                              hipStream_t stream) {
    const float* in = (const float*)d_in[0];
    float* out = (float*)d_out;
    const int npos = in_sizes[0] / D;        // 8192
    const int nblk = npos / POSPB;           // 2048
    moment_kernel<<<nblk, 256, 0, stream>>>(in, out);
}

// Round 5
// 162.306 us; speedup vs baseline: 1.1118x; 1.0544x over previous
//
#include <hip/hip_runtime.h>
#include <stdint.h>

// Moment features: all monomials of degree <= 4 over 16 latent dims.
// Output [8192, 4845] fp32 (~158.8 MB) -> pure HBM-write-bound (~27 us floor).
//
// Every channel of order k is prefix_feat(order k-1) * x[j]; reference
// enumeration makes these prefix-major runs, so the order<=3 features (969)
// are exactly output channels 0..968. One constexpr table drives both LDS
// compute phases and the store phase; entries bake BYTE offsets
// ((p*STRIDE+A)*4 | (p*STRIDE+B)*4 << 16) so a store-phase LDS read is a
// single addr-add. The 19 per-lane table entries are preloaded into
// registers at kernel entry (L2 latency hides under staging phases), and the
// store loop is fully unrolled -> 19 independent LDS->mul->store chains for
// the scheduler to pipeline. Plain stores (nontemporal was -25% measured);
// no min-occupancy launch bound (the forced 64-VGPR cap in r4 caused spills;
// fill kernel proves ~10% occupancy saturates write BW).

#define D      16
#define NC     4845           // 1 + 16 + 136 + 816 + 3876 = C(20,4)
#define NPAD   4864           // 19*256 float4 chunks (padded, pad entries = 0)
#define POSPB  4              // rows per block; 4*4845 dwords = 4845 float4s
#define STRIDE 969            // LDS slots/pos: 1.0, x[16], o2[136], o3[816]
#define NIT    19             // store iterations per thread

typedef float    f4_t __attribute__((ext_vector_type(4)));
typedef uint32_t u4_t __attribute__((ext_vector_type(4)));

struct alignas(16) Tables {
    uint32_t chunk[NPAD * 4]; // per flat dword of a 4-row group (byte offs)
};

static constexpr Tables build_tables() {
    Tables t{};
    // ---- per-channel (A = prefix slot, B = x slot), reference order ----
    unsigned short A[NC] = {}, B[NC] = {};
    int pos = 0;
    A[pos] = 0; B[pos] = 0; ++pos;                        // ones: 1*1
    for (int i = 0; i < D; ++i) { A[pos] = 0; B[pos] = (unsigned short)(1 + i); ++pos; }
    long c[D] = {};
    for (int i = 0; i < D; ++i) c[i] = 1;
    int baseprev = 1;                       // slot base of previous-order feats
    const int basecur[3] = {17, 153, 969};
    for (int it = 0; it < 3; ++it) {
        long S[D] = {};
        long acc = 0;
        for (int i = D - 1; i >= 0; --i) { acc += c[i]; S[i] = acc; }
        const long n = S[0];
        long off[D] = {};
        for (int i = 0; i < D; ++i) off[i] = n - S[i];
        for (long k = 0; k < n; ++k)                      // np.nonzero row-major
            for (int j = 0; j < D; ++j)
                if (k >= off[j]) {
                    A[pos] = (unsigned short)(baseprev + (int)k);
                    B[pos] = (unsigned short)(1 + j);
                    ++pos;
                }
        baseprev = basecur[it];
        for (int i = 0; i < D; ++i) c[i] = S[i];
    }
    // ---- flat dword table for a 4-row group, byte offsets, p*STRIDE baked --
    for (int f = 0; f < NPAD * 4; ++f) {
        const int p = f / NC;
        const int ch = f - p * NC;
        if (p < POSPB)
            t.chunk[f] = (uint32_t)((p * STRIDE + A[ch]) * 4)
                       | ((uint32_t)((p * STRIDE + B[ch]) * 4) << 16);
        else
            t.chunk[f] = 0;   // pad: reads lds[0]*lds[0]; store masked off
    }
    return t;
}

__device__ const Tables d_tables = build_tables();

__global__ __launch_bounds__(256) void moment_kernel(const float* __restrict__ in,
                                                     float* __restrict__ out) {
    __shared__ float lds[POSPB * STRIDE];   // 15504 B
    const int tid = threadIdx.x;
    const int blk = blockIdx.x;
    const uint32_t* __restrict__ dtab = d_tables.chunk;
    const u4_t* __restrict__ tab4 = (const u4_t*)dtab;

    // ---- preload per-lane store table into registers; latency hides under
    //      the staging/compute phases below (fully unrolled -> stays in regs)
    u4_t e[NIT];
    #pragma unroll
    for (int i = 0; i < NIT; ++i) e[i] = tab4[tid + 256 * i];

    // ---- stage x: 4 rows * 16 floats, coalesced; 1.0 identity slot per row
    if (tid < 64) {
        const float v = in[(size_t)blk * (POSPB * D) + tid];
        lds[(tid >> 4) * STRIDE + 1 + (tid & 15)] = v;
    } else if (tid < 68) {
        lds[(tid - 64) * STRIDE] = 1.0f;
    }
    __syncthreads();

    // ---- order-2 feats: 136 x 4 pos (x[k]*x[j], exact reference association)
    for (int i = tid; i < 136 * POSPB; i += 256) {
        const int ch = 17 + (i >> 2);
        const int po = (i & 3) * STRIDE;
        const uint32_t t = dtab[ch];                  // p=0 entry: byte offs
        lds[po + ch] = lds[po + ((t & 0xFFFFu) >> 2)] * lds[po + (t >> 18)];
    }
    __syncthreads();

    // ---- order-3 feats: 816 x 4 pos (prev * x, exact reference association)
    for (int i = tid; i < 816 * POSPB; i += 256) {
        const int ch = 153 + (i >> 2);
        const int po = (i & 3) * STRIDE;
        const uint32_t t = dtab[ch];
        lds[po + ch] = lds[po + ((t & 0xFFFFu) >> 2)] * lds[po + (t >> 18)];
    }
    __syncthreads();

    // ---- store phase: 19 independent LDS->mul->store chains, fully unrolled
    f4_t* __restrict__ ochunk = (f4_t*)(out + (size_t)blk * (NC * POSPB));
    const char* __restrict__ lb = (const char*)lds;
    #pragma unroll
    for (int i = 0; i < NIT; ++i) {
        const int q = tid + i * 256;
        f4_t v;
        v.x = *(const float*)(lb + (e[i].x & 0xFFFFu)) * *(const float*)(lb + (e[i].x >> 16));
        v.y = *(const float*)(lb + (e[i].y & 0xFFFFu)) * *(const float*)(lb + (e[i].y >> 16));
        v.z = *(const float*)(lb + (e[i].z & 0xFFFFu)) * *(const float*)(lb + (e[i].z >> 16));
        v.w = *(const float*)(lb + (e[i].w & 0xFFFFu)) * *(const float*)(lb + (e[i].w >> 16));
        if (q < NC) ochunk[q] = v;
    }
}

extern "C" void kernel_launch(void* const* d_in, const int* in_sizes, int n_in,
                              void* d_out, int out_size, void* d_ws, size_t ws_size,
                              hipStream_t stream) {
    const float* in = (const float*)d_in[0];
    float* out = (float*)d_out;
    const int npos = in_sizes[0] / D;        // 8192
    const int nblk = npos / POSPB;           // 2048
    moment_kernel<<<nblk, 256, 0, stream>>>(in, out);
}